// Round 11
// baseline (203.011 us; speedup 1.0000x reference)
//
#include <hip/hip_runtime.h>
#include <math.h>

#define N 4096
#define D 128
#define KSEL 32          // 0-indexed order statistic (33rd smallest)
#define ALPHA_C 16.0f

typedef short bf16x8 __attribute__((ext_vector_type(8)));
typedef float f32x4  __attribute__((ext_vector_type(4)));

__device__ inline float waveSumF(float v){
  #pragma unroll
  for (int o = 32; o; o >>= 1) v += __shfl_xor(v, o);
  return v;
}
__device__ inline int waveSumI(int v){
  #pragma unroll
  for (int o = 32; o; o >>= 1) v += __shfl_xor(v, o);
  return v;
}
__device__ inline float waveMinF(float v){
  #pragma unroll
  for (int o = 32; o; o >>= 1) v = fminf(v, __shfl_xor(v, o));
  return v;
}
// order-preserving float<->uint key (monotone bijection)
__device__ inline unsigned fkey(float f){
  unsigned u = __float_as_uint(f);
  return u ^ ((u >> 31) ? 0xFFFFFFFFu : 0x80000000u);
}
__device__ inline float fkey_inv(unsigned u){
  unsigned bits = (u & 0x80000000u) ? (u ^ 0x80000000u) : ~u;
  return __uint_as_float(bits);
}
// fp32 -> bf16 bits, round-to-nearest-even
__device__ inline unsigned short f2bf(float x){
  unsigned u = __float_as_uint(x);
  return (unsigned short)((u + 0x7FFFu + ((u >> 16) & 1u)) >> 16);
}
__device__ inline float bf2f(unsigned short h){
  return __uint_as_float(((unsigned)h) << 16);
}

// --- kernel 1: normalize; emit bf16 hi/lo split (row-major) + sq; zero accum
__global__ __launch_bounds__(256) void knorm(const float* __restrict__ in,
                                             unsigned short* __restrict__ xh,
                                             unsigned short* __restrict__ xl,
                                             float* __restrict__ sq,
                                             double* __restrict__ accum,
                                             unsigned* __restrict__ ctr){
  if (blockIdx.x == 0 && threadIdx.x < 5){
    if (threadIdx.x < 4) accum[threadIdx.x] = 0.0;
    else *ctr = 0u;
  }
  const int row  = blockIdx.x * 4 + (threadIdx.x >> 6);
  const int lane = threadIdx.x & 63;
  const float* p = in + (size_t)row * D;
  float e0 = p[lane], e1 = p[lane + 64];
  float s = waveSumF(e0*e0 + e1*e1);
  float inv = 1.0f / sqrtf(s);
  float x0 = e0 * inv, x1 = e1 * inv;
  float s2 = waveSumF(x0*x0 + x1*x1);      // faithful: sq from normalized x
  unsigned short h0 = f2bf(x0);  unsigned short l0 = f2bf(x0 - bf2f(h0));
  unsigned short h1 = f2bf(x1);  unsigned short l1 = f2bf(x1 - bf2f(h1));
  xh[(size_t)row * D + lane]      = h0;
  xh[(size_t)row * D + lane + 64] = h1;
  xl[(size_t)row * D + lane]      = l0;
  xl[(size_t)row * D + lane + 64] = l1;
  if (lane == 0) sq[row] = s2;
}

// --- kernel 2: MFMA Gram tiles (128x128/block); transposed f32x4 epilogue.
// dist is exactly symmetric, and the C/D fragment's reg axis is 4 CONSECUTIVE
// rows at one column -> storing dist[j*N+i] gives 8 dwordx4 stores/lane
// instead of 32 scattered dword stores (R10 epilogue).
__global__ __launch_bounds__(512, 2) void kdot(const unsigned short* __restrict__ xh,
                                               const unsigned short* __restrict__ xl,
                                               const float* __restrict__ sq,
                                               float* __restrict__ dist){
  const int lane = threadIdx.x & 63;
  const int w    = threadIdx.x >> 6;      // 8 waves: 2 (rows) x 4 (cols)
  const int wr   = w >> 2, wc = w & 3;
  const int i0   = blockIdx.y * 128;
  const int j0   = blockIdx.x * 128;

  const int rA = i0 + 64*wr + (lane & 15);  // + 16*tr
  const int cB = j0 + 32*wc + (lane & 15);  // + 16*tc
  const int kb = (lane >> 4) * 8;           // + 32*ks

  f32x4 acc[4][2];
  #pragma unroll
  for (int tr = 0; tr < 4; ++tr)
    #pragma unroll
    for (int tc = 0; tc < 2; ++tc) acc[tr][tc] = (f32x4){0.f,0.f,0.f,0.f};

  #pragma unroll
  for (int ks = 0; ks < 4; ++ks){
    const int k = 32*ks + kb;
    bf16x8 ah[4], al[4], bh[2], bl[2];
    #pragma unroll
    for (int tr = 0; tr < 4; ++tr){
      ah[tr] = *(const bf16x8*)(xh + (size_t)(rA + 16*tr) * D + k);
      al[tr] = *(const bf16x8*)(xl + (size_t)(rA + 16*tr) * D + k);
    }
    #pragma unroll
    for (int tc = 0; tc < 2; ++tc){
      bh[tc] = *(const bf16x8*)(xh + (size_t)(cB + 16*tc) * D + k);
      bl[tc] = *(const bf16x8*)(xl + (size_t)(cB + 16*tc) * D + k);
    }
    #pragma unroll
    for (int tr = 0; tr < 4; ++tr)
      #pragma unroll
      for (int tc = 0; tc < 2; ++tc){
        acc[tr][tc] = __builtin_amdgcn_mfma_f32_16x16x32_bf16(ah[tr], bh[tc], acc[tr][tc], 0, 0, 0);
        acc[tr][tc] = __builtin_amdgcn_mfma_f32_16x16x32_bf16(ah[tr], bl[tc], acc[tr][tc], 0, 0, 0);
        acc[tr][tc] = __builtin_amdgcn_mfma_f32_16x16x32_bf16(al[tr], bh[tc], acc[tr][tc], 0, 0, 0);
      }
  }

  // epilogue: value(i,j) = sq_i + sq_j - 2*dot, stored at dist[j][i..i+3]
  const int icol = i0 + 64*wr + 4*(lane >> 4);   // + 16*tr, +reg in float4
  const int jrow = j0 + 32*wc + (lane & 15);     // + 16*tc
  #pragma unroll
  for (int tr = 0; tr < 4; ++tr){
    const int ib = icol + 16*tr;
    const float4 sqi4 = *(const float4*)(sq + ib);
    #pragma unroll
    for (int tc = 0; tc < 2; ++tc){
      const int j = jrow + 16*tc;
      const float sqj = sq[j];
      float4 v;
      v.x = sqi4.x + sqj - 2.0f * acc[tr][tc][0];
      v.y = sqi4.y + sqj - 2.0f * acc[tr][tc][1];
      v.z = sqi4.z + sqj - 2.0f * acc[tr][tc][2];
      v.w = sqi4.w + sqj - 2.0f * acc[tr][tc][3];
      *(float4*)(dist + (size_t)j * N + ib) = v;
    }
  }
}

// --- kernel 3: per-row stats + exact selection + logits (wave per row).
// Selection = key-space bisection to FULL convergence on the register-held
// row: zero LDS, zero atomics, no serial dependent-latency loop (R10's
// rank-select loop was ~192 dependent LDS broadcasts -> the 79us tail).
__global__ __launch_bounds__(512, 2) void ksel(const float* __restrict__ dist,
                                               const int* __restrict__ tgt,
                                               double* __restrict__ accum,
                                               unsigned* __restrict__ ctr,
                                               float* __restrict__ out){
  __shared__ float scrP[8], scrN[8], lsSh[8], acSh[8];

  const int tid  = threadIdx.x;
  const int lane = tid & 63;
  const int w    = tid >> 6;
  const int r    = blockIdx.x * 8 + w;    // owned row

  const int tw = tgt[r];
  const float4* drow = (const float4*)(dist + (size_t)r * N);
  const int4*   tg4  = (const int4*)tgt;

  // load row + fused stats (bsum over true values incl. diag; diag->INF in d)
  float d[64];
  float pb = 0.f, posd = 0.f, negd = 0.f, pm = INFINITY;
  #pragma unroll
  for (int u = 0; u < 16; ++u){
    float4 v = drow[64*u + lane];
    int4  tg = tg4 [64*u + lane];
    const int jb = 4*(64*u + lane);
    #pragma unroll
    for (int q = 0; q < 4; ++q){
      float dj = (q==0)?v.x:(q==1)?v.y:(q==2)?v.z:v.w;
      int   tj = (q==0)?tg.x:(q==1)?tg.y:(q==2)?tg.z:tg.w;
      const bool diag = (jb + q == r);
      pb += dj;                            // base includes true diag value (ref)
      const bool same = (tj == tw);
      if (same && !diag){ posd += dj; pm = fminf(pm, dj); }
      if (!same) negd += dj;
      d[4*u + q] = diag ? INFINITY : dj;
    }
  }
  const float base   = waveSumF(pb) * (1.0f / (float)N);
  const float minpos = waveMinF(pm);
  { float v = waveSumF(posd); if (lane == 0) scrP[w] = v; }
  { float v = waveSumF(negd); if (lane == 0) scrN[w] = v; }

  // bisection to convergence: val(lo) is EXACTLY the 33rd smallest
  // (invariant: cnt(d < val(lo)) <= 32, cnt(d < val(hi)) >= 33, hi = lo+1)
  float thr;
  {
    float dmin = INFINITY;
    #pragma unroll
    for (int s = 0; s < 64; ++s) dmin = fminf(dmin, d[s]);
    dmin = waveMinF(dmin);

    unsigned lo = fkey(dmin);              // cnt(d < dmin) == 0 < 33
    unsigned hi = fkey(4.5f);              // all real dists <= 4+eps -> cnt >= 33
    while (hi - lo > 1u){
      float loV = fkey_inv(lo), hiV = fkey_inv(hi);
      unsigned mid = fkey(0.5f * (loV + hiV));       // value-space pivot
      mid = (mid <= lo) ? lo + 1u : ((mid >= hi) ? hi - 1u : mid);
      float pv = fkey_inv(mid);
      int cc = 0;
      #pragma unroll
      for (int s = 0; s < 64; ++s) cc += (d[s] < pv) ? 1 : 0;
      cc = waveSumI(cc);
      if (cc < KSEL + 1) lo = mid;
      else hi = mid;
    }
    thr = fkey_inv(lo);
  }

  // logits (strict '<', diag is INF)
  {
    float pls = 0.f, nls = 0.f; int pcnt = 0;
    #pragma unroll
    for (int u = 0; u < 16; ++u){
      int4 tg = tg4[64*u + lane];
      #pragma unroll
      for (int q = 0; q < 4; ++q){
        float dvq = d[4*u + q];
        int   tj  = (q==0)?tg.x:(q==1)?tg.y:(q==2)?tg.z:tg.w;
        if (dvq < thr){
          float e = expf(ALPHA_C * (base - dvq));
          if (tj == tw){ pls += e; pcnt++; } else nls += e;
        }
      }
    }
    pls = waveSumF(pls); nls = waveSumF(nls); pcnt = waveSumI(pcnt);
    if (lane == 0){
      float plogit = (pcnt > 0) ? pls : expf(ALPHA_C * (base - minpos));
      float li = -logf(plogit / (plogit + nls));
      lsSh[w] = li;
      acSh[w] = (li < 0.6f) ? 1.f : 0.f;
    }
  }
  __syncthreads();
  if (tid == 0){
    float ls = 0.f, ac = 0.f; double sp = 0.0, sn = 0.0;
    #pragma unroll
    for (int q = 0; q < 8; ++q){
      ls += lsSh[q]; ac += acSh[q];
      sp += (double)scrP[q]; sn += (double)scrN[q];
    }
    atomicAdd(&accum[0], (double)ls);
    atomicAdd(&accum[1], (double)ac);
    atomicAdd(&accum[2], sp);
    atomicAdd(&accum[3], sn);
    __threadfence();
    unsigned done = atomicAdd(ctr, 1u);
    if (done == gridDim.x - 1){
      double a0 = atomicAdd(&accum[0], 0.0);
      double a1 = atomicAdd(&accum[1], 0.0);
      double a2 = atomicAdd(&accum[2], 0.0);
      double a3 = atomicAdd(&accum[3], 0.0);
      out[0] = (float)(a0 / (double)N);
      out[1] = (float)(a1 / (double)N);
      out[2] = (float)(a2 / ((double)N * 7.0));
      out[3] = (float)(a3 / ((double)N * (double)(N - 8)));
    }
  }
}

extern "C" void kernel_launch(void* const* d_in, const int* in_sizes, int n_in,
                              void* d_out, int out_size, void* d_ws, size_t ws_size,
                              hipStream_t stream){
  (void)in_sizes; (void)n_in; (void)out_size; (void)ws_size;
  const float* in  = (const float*)d_in[0];
  const int*   tgt = (const int*)d_in[1];
  float* out = (float*)d_out;

  char* ws = (char*)d_ws;
  unsigned short* xh = (unsigned short*)(ws);            // 1 MB
  unsigned short* xl = (unsigned short*)(ws + 1048576);  // 1 MB
  float*    sq    = (float*)(ws + 2097152);              // 16 KB
  double*   accum = (double*)(ws + 2113536);             // 32 B (8-aligned)
  unsigned* ctr   = (unsigned*)(ws + 2113568);           // 4 B
  float*    dist  = (float*)(ws + 2113792);              // 64 MiB (256-aligned)

  knorm<<<N/4, 256, 0, stream>>>(in, xh, xl, sq, accum, ctr);
  dim3 g(N/128, N/128);
  kdot <<<g, 512, 0, stream>>>(xh, xl, sq, dist);
  ksel <<<N/8, 512, 0, stream>>>(dist, tgt, accum, ctr, out);
}

// Round 12
// 164.841 us; speedup vs baseline: 1.2316x; 1.2316x over previous
//
#include <hip/hip_runtime.h>
#include <math.h>

#define N 4096
#define D 128
#define KSEL 32          // 0-indexed order statistic (33rd smallest)
#define ALPHA_C 16.0f
#define QS  16384.0f     // dist quantization scale (d in [0,4) -> [0,65536))
#define QSI (1.0f/16384.0f)

typedef short bf16x8 __attribute__((ext_vector_type(8)));
typedef float f32x4  __attribute__((ext_vector_type(4)));

__device__ inline float waveSumF(float v){
  #pragma unroll
  for (int o = 32; o; o >>= 1) v += __shfl_xor(v, o);
  return v;
}
__device__ inline int waveSumI(int v){
  #pragma unroll
  for (int o = 32; o; o >>= 1) v += __shfl_xor(v, o);
  return v;
}
__device__ inline float waveMinF(float v){
  #pragma unroll
  for (int o = 32; o; o >>= 1) v = fminf(v, __shfl_xor(v, o));
  return v;
}
// fp32 -> bf16 bits, round-to-nearest-even
__device__ inline unsigned short f2bf(float x){
  unsigned u = __float_as_uint(x);
  return (unsigned short)((u + 0x7FFFu + ((u >> 16) & 1u)) >> 16);
}
__device__ inline float bf2f(unsigned short h){
  return __uint_as_float(((unsigned)h) << 16);
}

// --- kernel 1: normalize; bf16 hi/lo split + sq + u16 targets; zero accum
__global__ __launch_bounds__(256) void knorm(const float* __restrict__ in,
                                             const int* __restrict__ tgt,
                                             unsigned short* __restrict__ xh,
                                             unsigned short* __restrict__ xl,
                                             float* __restrict__ sq,
                                             unsigned short* __restrict__ t16,
                                             double* __restrict__ accum,
                                             unsigned* __restrict__ ctr){
  if (blockIdx.x == 0 && threadIdx.x < 5){
    if (threadIdx.x < 4) accum[threadIdx.x] = 0.0;
    else *ctr = 0u;
  }
  const int row  = blockIdx.x * 4 + (threadIdx.x >> 6);
  const int lane = threadIdx.x & 63;
  const float* p = in + (size_t)row * D;
  float e0 = p[lane], e1 = p[lane + 64];
  float s = waveSumF(e0*e0 + e1*e1);
  float inv = 1.0f / sqrtf(s);
  float x0 = e0 * inv, x1 = e1 * inv;
  float s2 = waveSumF(x0*x0 + x1*x1);      // faithful: sq from normalized x
  unsigned short h0 = f2bf(x0);  unsigned short l0 = f2bf(x0 - bf2f(h0));
  unsigned short h1 = f2bf(x1);  unsigned short l1 = f2bf(x1 - bf2f(h1));
  xh[(size_t)row * D + lane]      = h0;
  xh[(size_t)row * D + lane + 64] = h1;
  xl[(size_t)row * D + lane]      = l0;
  xl[(size_t)row * D + lane + 64] = l1;
  if (lane == 0){ sq[row] = s2; t16[row] = (unsigned short)tgt[row]; }
}

// --- kernel 2: MFMA Gram tiles; quantize to u16; LDS-staged coalesced stores.
// R11's transposed f32 stores were 16-row scattered 64B fragments (write
// amplification). Now: tile -> LDS (pad 8 u16 => 2-way banks, free) -> 256B
// contiguous dwordx4 row stores. Write traffic 64MB scattered -> 32MB coalesced.
__global__ __launch_bounds__(512, 2) void kdot(const unsigned short* __restrict__ xh,
                                               const unsigned short* __restrict__ xl,
                                               const float* __restrict__ sq,
                                               unsigned short* __restrict__ dq){
  __shared__ unsigned short til[128][136];   // 34 KB
  const int lane = threadIdx.x & 63;
  const int w    = threadIdx.x >> 6;      // 8 waves: 2 (rows) x 4 (cols)
  const int wr   = w >> 2, wc = w & 3;
  const int i0   = blockIdx.y * 128;
  const int j0   = blockIdx.x * 128;

  const int rA = i0 + 64*wr + (lane & 15);  // + 16*tr
  const int cB = j0 + 32*wc + (lane & 15);  // + 16*tc
  const int kb = (lane >> 4) * 8;           // + 32*ks

  f32x4 acc[4][2];
  #pragma unroll
  for (int tr = 0; tr < 4; ++tr)
    #pragma unroll
    for (int tc = 0; tc < 2; ++tc) acc[tr][tc] = (f32x4){0.f,0.f,0.f,0.f};

  #pragma unroll
  for (int ks = 0; ks < 4; ++ks){
    const int k = 32*ks + kb;
    bf16x8 ah[4], al[4], bh[2], bl[2];
    #pragma unroll
    for (int tr = 0; tr < 4; ++tr){
      ah[tr] = *(const bf16x8*)(xh + (size_t)(rA + 16*tr) * D + k);
      al[tr] = *(const bf16x8*)(xl + (size_t)(rA + 16*tr) * D + k);
    }
    #pragma unroll
    for (int tc = 0; tc < 2; ++tc){
      bh[tc] = *(const bf16x8*)(xh + (size_t)(cB + 16*tc) * D + k);
      bl[tc] = *(const bf16x8*)(xl + (size_t)(cB + 16*tc) * D + k);
    }
    #pragma unroll
    for (int tr = 0; tr < 4; ++tr)
      #pragma unroll
      for (int tc = 0; tc < 2; ++tc){
        acc[tr][tc] = __builtin_amdgcn_mfma_f32_16x16x32_bf16(ah[tr], bh[tc], acc[tr][tc], 0, 0, 0);
        acc[tr][tc] = __builtin_amdgcn_mfma_f32_16x16x32_bf16(ah[tr], bl[tc], acc[tr][tc], 0, 0, 0);
        acc[tr][tc] = __builtin_amdgcn_mfma_f32_16x16x32_bf16(al[tr], bh[tc], acc[tr][tc], 0, 0, 0);
      }
  }

  // quantize into LDS tile (C/D mapping HW-verified in R8: absmax 0.0)
  const int il_base = 64*wr + 4*(lane >> 4);
  const int jl_base = 32*wc + (lane & 15);
  #pragma unroll
  for (int tr = 0; tr < 4; ++tr){
    const int il4 = il_base + 16*tr;
    const float4 sqi4 = *(const float4*)(sq + i0 + il4);
    #pragma unroll
    for (int tc = 0; tc < 2; ++tc){
      const int jl = jl_base + 16*tc;
      const float sqj = sq[j0 + jl];
      #pragma unroll
      for (int reg = 0; reg < 4; ++reg){
        const float sqi = (reg==0)?sqi4.x:(reg==1)?sqi4.y:(reg==2)?sqi4.z:sqi4.w;
        float v = sqi + sqj - 2.0f * acc[tr][tc][reg];
        int q = (int)(v * QS + 0.5f);
        q = (q < 0) ? 0 : ((q > 65535) ? 65535 : q);
        if (i0 + il4 + reg == j0 + jl) q = 65535;   // diag sentinel (== ref inf)
        til[il4 + reg][jl] = (unsigned short)q;
      }
    }
  }
  __syncthreads();

  // coalesced store: 16 threads/row, 256B contiguous per row
  #pragma unroll
  for (int it = 0; it < 4; ++it){
    const int row = (threadIdx.x >> 4) + 32 * it;
    const int col = (threadIdx.x & 15) * 8;
    uint4 v = *(const uint4*)&til[row][col];
    *(uint4*)(dq + (size_t)(i0 + row) * N + j0 + col) = v;
  }
}

// --- kernel 3: wave-per-row; u16 row load (8KB), integer-grid bisection
// (exactly 16 iters; thr = lo/16384 is EXACTLY the 33rd smallest since all
// values are multiples of 1/16384), branchy logits on ~33 selected values.
__global__ __launch_bounds__(512, 2) void ksel(const unsigned short* __restrict__ dq,
                                               const unsigned short* __restrict__ t16,
                                               const int* __restrict__ tgt,
                                               double* __restrict__ accum,
                                               unsigned* __restrict__ ctr,
                                               float* __restrict__ out){
  __shared__ float scrP[8], scrN[8], lsSh[8], acSh[8];

  const int tid  = threadIdx.x;
  const int lane = tid & 63;
  const int w    = tid >> 6;
  const int r    = blockIdx.x * 8 + w;    // owned row

  const int tw = tgt[r];
  const uint4* qrow = (const uint4*)(dq + (size_t)r * N);
  const uint4* trow = (const uint4*)t16;

  float d[64];
  unsigned long long sameMask = 0ull;
  float pb = 0.f, posd = 0.f, negd = 0.f, pm = INFINITY;

  #pragma unroll
  for (int u = 0; u < 8; ++u){
    const uint4 q4 = qrow[lane + 64*u];
    const uint4 t4 = trow[lane + 64*u];
    const int jb = (lane + 64*u) * 8;
    #pragma unroll
    for (int k = 0; k < 8; ++k){
      const unsigned qdw = (k<2)?q4.x:(k<4)?q4.y:(k<6)?q4.z:q4.w;  // static
      const unsigned tdw = (k<2)?t4.x:(k<4)?t4.y:(k<6)?t4.z:t4.w;
      const unsigned q  = (k & 1) ? (qdw >> 16) : (qdw & 0xFFFFu);
      const int      tj = (int)((k & 1) ? (tdw >> 16) : (tdw & 0xFFFFu));
      const float dj = (float)q * QSI;
      const bool diag = (jb + k == r);
      const bool same = (tj == tw);
      if (!diag) pb += dj;               // ref diag ~0; our sentinel excluded
      if (same && !diag){ posd += dj; pm = fminf(pm, dj); }
      if (!same) negd += dj;
      const int s = 8*u + k;
      d[s] = diag ? INFINITY : dj;
      if (same) sameMask |= 1ull << s;
    }
  }
  const float base   = waveSumF(pb) * (1.0f / (float)N);
  const float minpos = waveMinF(pm);
  { float v = waveSumF(posd); if (lane == 0) scrP[w] = v; }
  { float v = waveSumF(negd); if (lane == 0) scrN[w] = v; }

  // integer-grid bisection: 16 iterations, exact
  float thrV;
  {
    unsigned lo = 0u, hi = 65536u;
    while (hi - lo > 1u){
      const unsigned mid = (lo + hi) >> 1;
      const float pv = (float)mid * QSI;
      int cc = 0;
      #pragma unroll
      for (int s = 0; s < 64; ++s) cc += (d[s] < pv) ? 1 : 0;
      cc = waveSumI(cc);
      if (cc < KSEL + 1) lo = mid; else hi = mid;
    }
    thrV = (float)lo * QSI;   // exact 33rd-smallest stored value
  }

  // logits (strict '<'; diag is INF; ~33 selected -> branches mostly skip)
  {
    float pls = 0.f, nls = 0.f; int pcnt = 0;
    #pragma unroll
    for (int s = 0; s < 64; ++s){
      if (d[s] < thrV){
        const float e = expf(ALPHA_C * (base - d[s]));
        if ((sameMask >> s) & 1ull){ pls += e; pcnt++; } else nls += e;
      }
    }
    pls = waveSumF(pls); nls = waveSumF(nls); pcnt = waveSumI(pcnt);
    if (lane == 0){
      const float plogit = (pcnt > 0) ? pls : expf(ALPHA_C * (base - minpos));
      const float li = -logf(plogit / (plogit + nls));
      lsSh[w] = li;
      acSh[w] = (li < 0.6f) ? 1.f : 0.f;
    }
  }
  __syncthreads();
  if (tid == 0){
    float ls = 0.f, ac = 0.f; double sp = 0.0, sn = 0.0;
    #pragma unroll
    for (int q = 0; q < 8; ++q){
      ls += lsSh[q]; ac += acSh[q];
      sp += (double)scrP[q]; sn += (double)scrN[q];
    }
    atomicAdd(&accum[0], (double)ls);
    atomicAdd(&accum[1], (double)ac);
    atomicAdd(&accum[2], sp);
    atomicAdd(&accum[3], sn);
    __threadfence();
    unsigned done = atomicAdd(ctr, 1u);
    if (done == gridDim.x - 1){
      double a0 = atomicAdd(&accum[0], 0.0);
      double a1 = atomicAdd(&accum[1], 0.0);
      double a2 = atomicAdd(&accum[2], 0.0);
      double a3 = atomicAdd(&accum[3], 0.0);
      out[0] = (float)(a0 / (double)N);
      out[1] = (float)(a1 / (double)N);
      out[2] = (float)(a2 / ((double)N * 7.0));
      out[3] = (float)(a3 / ((double)N * (double)(N - 8)));
    }
  }
}

extern "C" void kernel_launch(void* const* d_in, const int* in_sizes, int n_in,
                              void* d_out, int out_size, void* d_ws, size_t ws_size,
                              hipStream_t stream){
  (void)in_sizes; (void)n_in; (void)out_size; (void)ws_size;
  const float* in  = (const float*)d_in[0];
  const int*   tgt = (const int*)d_in[1];
  float* out = (float*)d_out;

  char* ws = (char*)d_ws;
  unsigned short* xh  = (unsigned short*)(ws);             // 1 MB
  unsigned short* xl  = (unsigned short*)(ws + 1048576);   // 1 MB
  float*          sq  = (float*)(ws + 2097152);            // 16 KB
  unsigned short* t16 = (unsigned short*)(ws + 2113536);   // 8 KB
  double*       accum = (double*)(ws + 2121728);           // 32 B (8-aligned)
  unsigned*       ctr = (unsigned*)(ws + 2121760);         // 4 B
  unsigned short* dq  = (unsigned short*)(ws + 2129920);   // 32 MiB (256-aligned)

  knorm<<<N/4, 256, 0, stream>>>(in, tgt, xh, xl, sq, t16, accum, ctr);
  dim3 g(N/128, N/128);
  kdot <<<g, 512, 0, stream>>>(xh, xl, sq, dq);
  ksel <<<N/8, 512, 0, stream>>>(dq, t16, tgt, accum, ctr, out);
}